// Round 1
// baseline (749.821 us; speedup 1.0000x reference)
//
#include <hip/hip_runtime.h>
#include <math.h>

// GlobalAttentionPool: fused linear-score + segment softmax + weighted pool.
// Single pass over x (512 MB) using online softmax per segment.
// batch is sorted -> segments contiguous; one block per segment.

#define DIM 128

__device__ __forceinline__ int lower_bound_i32(const int* __restrict__ a, int n, int key) {
    int lo = 0, hi = n;
    while (lo < hi) {
        int mid = (lo + hi) >> 1;
        if (a[mid] < key) lo = mid + 1; else hi = mid;
    }
    return lo;
}

__global__ __launch_bounds__(256) void gap_online_kernel(
    const float* __restrict__ x,
    const int*   __restrict__ batch,
    const float* __restrict__ W,
    const float* __restrict__ bias,
    float*       __restrict__ out,
    int N)
{
    const int seg  = blockIdx.x;
    const int tid  = threadIdx.x;
    const int wave = tid >> 6;   // 0..3
    const int lane = tid & 63;   // 0..63

    // Segment range [start, end). Uniform across block; loads are scalar-ish
    // and hit L2/L3 after first touch.
    const int start = lower_bound_i32(batch, N, seg);
    const int end   = lower_bound_i32(batch, N, seg + 1);

    // Per-lane W fragment: lane j holds W[2j], W[2j+1].
    const float2 wv = ((const float2*)W)[lane];
    const float  b0 = bias[0];

    // Online softmax state (per wave, distributed across lanes for acc).
    float  m   = -INFINITY;
    float  l   = 0.0f;
    float2 acc = make_float2(0.0f, 0.0f);

    for (int r = start + wave; r < end; r += 4) {
        const float2 xv = ((const float2*)(x + (size_t)r * DIM))[lane];

        // score = dot(x[r], W) + b : partial per lane, butterfly reduce over 64 lanes
        float s = xv.x * wv.x + xv.y * wv.y;
        #pragma unroll
        for (int off = 32; off > 0; off >>= 1)
            s += __shfl_xor(s, off, 64);
        s += b0;

        // Branchless online-softmax update; x row still in registers.
        const float m_new = fmaxf(m, s);
        const float alpha = __expf(m - m_new);   // exp(-inf)=0 on first row
        const float w     = __expf(s - m_new);
        l     = l * alpha + w;
        acc.x = acc.x * alpha + w * xv.x;
        acc.y = acc.y * alpha + w * xv.y;
        m     = m_new;
    }

    // Merge the 4 per-wave online-softmax states (associative combine).
    __shared__ float sm[4];
    __shared__ float sl[4];
    __shared__ float sacc[4][DIM];

    sacc[wave][2 * lane]     = acc.x;
    sacc[wave][2 * lane + 1] = acc.y;
    if (lane == 0) { sm[wave] = m; sl[wave] = l; }
    __syncthreads();

    if (tid < DIM) {
        float m_tot = fmaxf(fmaxf(sm[0], sm[1]), fmaxf(sm[2], sm[3]));
        float num = 0.0f, den = 0.0f;
        #pragma unroll
        for (int w = 0; w < 4; ++w) {
            // Guard: empty-wave state (l==0, m==-inf) contributes nothing and
            // must not produce exp(-inf - -inf) = NaN.
            const float a = (sl[w] > 0.0f) ? __expf(sm[w] - m_tot) : 0.0f;
            num += sacc[w][tid] * a;
            den += sl[w] * a;
        }
        // Matches reference: attn = ex / (seg_sum + 1e-16); empty segment -> 0.
        out[(size_t)seg * DIM + tid] = (den > 0.0f) ? (num / (den + 1e-16f)) : 0.0f;
    }
}

extern "C" void kernel_launch(void* const* d_in, const int* in_sizes, int n_in,
                              void* d_out, int out_size, void* d_ws, size_t ws_size,
                              hipStream_t stream) {
    const float* x     = (const float*)d_in[0];
    // d_in[1] = edge_index (unused by the forward math)
    const int*   batch = (const int*)d_in[2];
    const float* W     = (const float*)d_in[3];
    const float* bias  = (const float*)d_in[4];
    float*       out   = (float*)d_out;

    const int N = in_sizes[2];          // number of nodes
    const int B = out_size / DIM;       // number of segments

    gap_online_kernel<<<B, 256, 0, stream>>>(x, batch, W, bias, out, N);
}

// Round 2
// 667.055 us; speedup vs baseline: 1.1241x; 1.1241x over previous
//
#include <hip/hip_runtime.h>
#include <math.h>

// GlobalAttentionPool: fused linear-score + segment softmax + weighted pool.
// Single pass over x (512 MB) using online softmax per segment.
// batch is sorted -> segments contiguous; one block per segment.
//
// Round-2 restructure vs round-1 (750 us, latency-bound):
//  - 8 rows per wave-iteration: 4 independent float4 loads (2 rows/load,
//    32 lanes/row) -> 4 KB in flight per wave instead of 512 B.
//  - Batched 5-step butterfly reduce (4 scores at once) -> lgkm waits
//    amortized 8x vs the per-row 6-step chain.
//  - Explicit next-tile prefetch to overlap HBM latency with the reduce.
//  - Segment offsets precomputed by a tiny kernel (replaces per-block
//    binary search over batch[1e6]).

#define DIM 128
#define NEG_HUGE (-3.0e38f)

// ---- Kernel 1: segment offset table from sorted batch -----------------
// off[s] = first index i with batch[i] >= s, for s in [0, B]; off[B] = N.
__global__ void seg_offsets_kernel(const int* __restrict__ batch,
                                   int* __restrict__ off, int N, int B) {
    int i = blockIdx.x * blockDim.x + threadIdx.x;
    if (i >= N) return;
    int bi = batch[i];
    int bp = (i == 0) ? -1 : batch[i - 1];
    for (int s = bp + 1; s <= bi; ++s) off[s] = i;
    if (i == N - 1) {
        for (int s = bi + 1; s <= B; ++s) off[s] = N;
    }
}

// ---- Kernel 2: fused online-softmax attention pool --------------------
__global__ __launch_bounds__(256) void gap_online_kernel(
    const float* __restrict__ x,
    const int*   __restrict__ off,
    const float* __restrict__ W,
    const float* __restrict__ bias,
    float*       __restrict__ out)
{
    const int seg  = blockIdx.x;
    const int tid  = threadIdx.x;
    const int wave = tid >> 6;   // 0..3
    const int lane = tid & 63;
    const int half = lane >> 5;  // which row of the float4-load pair
    const int hl   = lane & 31;  // lane within 32-lane row group

    const int start = off[seg];
    const int end   = off[seg + 1];

    // Lane hl of each half holds W[4*hl .. 4*hl+3].
    const float4 wv = ((const float4*)W)[hl];
    const float  b0 = bias[0];

    // Online-softmax state per (wave, half): acc distributed over 32 lanes.
    float  m = NEG_HUGE;
    float  l = 0.0f;
    float4 acc = make_float4(0.f, 0.f, 0.f, 0.f);

    // Tile: 8 rows per wave-iteration (k=0..3, 2 rows per float4 load),
    // 32 rows per block-iteration.
    int p = start + wave * 8;

    float4 xv[4];
    #pragma unroll
    for (int k = 0; k < 4; ++k) {
        int row = p + 2 * k + half;
        xv[k] = (row < end) ? ((const float4*)(x + (size_t)row * DIM))[hl]
                            : make_float4(0.f, 0.f, 0.f, 0.f);
    }

    for (; p < end; p += 32) {
        // Prefetch next tile while we reduce the current one.
        float4 xn[4];
        #pragma unroll
        for (int k = 0; k < 4; ++k) {
            int row = p + 32 + 2 * k + half;
            xn[k] = (row < end) ? ((const float4*)(x + (size_t)row * DIM))[hl]
                                : make_float4(0.f, 0.f, 0.f, 0.f);
        }

        // Partial dots for 8 rows (4 per half-wave).
        float s[4];
        #pragma unroll
        for (int k = 0; k < 4; ++k)
            s[k] = xv[k].x * wv.x + xv[k].y * wv.y + xv[k].z * wv.z + xv[k].w * wv.w;

        // Batched butterfly within each 32-lane half (masks <32 keep halves closed).
        #pragma unroll
        for (int offd = 16; offd > 0; offd >>= 1) {
            #pragma unroll
            for (int k = 0; k < 4; ++k)
                s[k] += __shfl_xor(s[k], offd, 64);
        }

        // Online-softmax state update; x rows still in registers.
        #pragma unroll
        for (int k = 0; k < 4; ++k) {
            int  row   = p + 2 * k + half;
            bool valid = row < end;
            float sk    = valid ? (s[k] + b0) : NEG_HUGE;
            float m_new = fmaxf(m, sk);
            float alpha = __expf(m - m_new);            // exp(0)=1 while empty
            float w     = valid ? __expf(sk - m_new) : 0.0f;
            l     = l * alpha + w;
            acc.x = acc.x * alpha + w * xv[k].x;
            acc.y = acc.y * alpha + w * xv[k].y;
            acc.z = acc.z * alpha + w * xv[k].z;
            acc.w = acc.w * alpha + w * xv[k].w;
            m     = m_new;
            xv[k] = xn[k];
        }
    }

    // ---- Merge 8 per-(wave,half) states (associative combine) ----
    __shared__ float sm[8];
    __shared__ float sl[8];
    __shared__ float sacc[8][DIM];

    const int sid = wave * 2 + half;
    sacc[sid][4 * hl + 0] = acc.x;
    sacc[sid][4 * hl + 1] = acc.y;
    sacc[sid][4 * hl + 2] = acc.z;
    sacc[sid][4 * hl + 3] = acc.w;
    if (hl == 0) { sm[sid] = m; sl[sid] = l; }
    __syncthreads();

    if (tid < DIM) {
        float m_tot = NEG_HUGE;
        #pragma unroll
        for (int h = 0; h < 8; ++h) m_tot = fmaxf(m_tot, sm[h]);
        float num = 0.0f, den = 0.0f;
        #pragma unroll
        for (int h = 0; h < 8; ++h) {
            float a = __expf(sm[h] - m_tot);  // empty state: exp(-huge)=0 (or 1 w/ l=0)
            num += sacc[h][tid] * a;
            den += sl[h] * a;
        }
        // Matches reference attn = ex / (seg_sum + 1e-16); empty segment -> 0/eps = 0.
        out[(size_t)seg * DIM + tid] = num / (den + 1e-16f);
    }
}

extern "C" void kernel_launch(void* const* d_in, const int* in_sizes, int n_in,
                              void* d_out, int out_size, void* d_ws, size_t ws_size,
                              hipStream_t stream) {
    const float* x     = (const float*)d_in[0];
    // d_in[1] = edge_index (unused by the forward math)
    const int*   batch = (const int*)d_in[2];
    const float* W     = (const float*)d_in[3];
    const float* bias  = (const float*)d_in[4];
    float*       out   = (float*)d_out;

    const int N = in_sizes[2];          // number of nodes
    const int B = out_size / DIM;       // number of segments

    int* off = (int*)d_ws;              // (B+1) ints, rewritten every launch

    seg_offsets_kernel<<<(N + 255) / 256, 256, 0, stream>>>(batch, off, N, B);
    gap_online_kernel<<<B, 256, 0, stream>>>(x, off, W, bias, out);
}